// Round 5
// baseline (103.006 us; speedup 1.0000x reference)
//
#include <hip/hip_runtime.h>
#include <math.h>

#define IN_CH 64
#define OUT_CH 64
#define M1 32
#define M2 32
#define HH 512
#define WW 512

// ---------------- workspace layout (floats) ----------------
// F   : [512][64]  cols 0..31 = cos(2pi k h/512), cols 32..63 = sin(...)
// FA  : [512][64]  cols 0..31 = cos, cols 32..63 = -sin   (stageA B-matrix)
// GT  : [64][512]  row j<32: cos(2pi j t/512); row j>=32: -sin(...)
// Xw0 : [64][512][64]  partial w-DFT (K-half 0)
// Xw1 : same, K-half 1
// XFp : [64 i][8 ht][2 reim][32 kx][32 ky]  partial h-DFT
// Gp  : [2 ic][64 o][32 kx][32 ky][2 lr/li] partial channel-mix
// G   : [64 o][64 m][64 j]  sign-expanded spectral matrix (scaled)
// Z   : aliases Xw0  [64 o][512 h][64 j]
static const size_t OFF_F   = 0;
static const size_t OFF_FA  = 32768;
static const size_t OFF_GT  = 65536;
static const size_t OFF_XW0 = 98304;
static const size_t OFF_XW1 = OFF_XW0 + (size_t)64*512*64;
static const size_t OFF_XFP = OFF_XW1 + (size_t)64*512*64;
static const size_t OFF_GP  = OFF_XFP + (size_t)64*8*2048;
static const size_t OFF_G   = OFF_GP  + (size_t)2*65536*2;
static const size_t OFF_Z   = OFF_XW0;   // alias: Xw0 dead after stageB

__device__ __forceinline__ void gload16(const float* g, float* l) {
    __builtin_amdgcn_global_load_lds(
        (const __attribute__((address_space(1))) void*)g,
        (__attribute__((address_space(3))) void*)l, 16, 0, 0);
}

__global__ void build_table(float* __restrict__ F, float* __restrict__ FA,
                            float* __restrict__ GT) {
    int idx = blockIdx.x * 256 + threadIdx.x;      // 0..32767
    int w = idx >> 6, j = idx & 63, k = j & 31;
    int m = (k * w) & 511;                          // exact angle reduction
    float ang = (6.283185307179586f / 512.0f) * (float)m;
    float s, c;
    sincosf(ang, &s, &c);
    F[idx] = (j < 32) ? c : s;
    float g = (j < 32) ? c : -s;
    FA[idx] = g;
    GT[(size_t)j * 512 + w] = g;
}

// Unified 64-wide GEMM tile: C[row][j] = sum_k A[row][k] * B[k][j]
// 256 threads, 64x64 C-tile per block, K = nK*64, global_load_lds staging.
__device__ __forceinline__ void gemm64_core(const float* __restrict__ Ab, int sA,
                                            const float* __restrict__ Bb, int sB,
                                            float* __restrict__ Cb, int sC, int nK) {
    __shared__ __align__(16) float as[4096];   // [row][k] linear
    __shared__ __align__(16) float bs[4096];   // [k][j]   linear
    int t = threadIdx.x;
    int tx = t & 15, ty = t >> 4;
    float acc[4][4] = {};
    for (int tt = 0; tt < nK; ++tt) {
#pragma unroll
        for (int p = 0; p < 4; ++p) {
            int flat = p * 1024 + t * 4;
            int row = flat >> 6, col = flat & 63;
            gload16(Ab + (size_t)row * sA + tt * 64 + col, &as[flat]);
            gload16(Bb + (size_t)(tt * 64 + row) * sB + col, &bs[flat]);
        }
        __syncthreads();
#pragma unroll 4
        for (int k0 = 0; k0 < 64; k0 += 4) {
            float4 av[4], bv[4];
#pragma unroll
            for (int r = 0; r < 4; ++r)
                av[r] = *(const float4*)&as[(ty * 4 + r) * 64 + k0];
#pragma unroll
            for (int kk = 0; kk < 4; ++kk)
                bv[kk] = *(const float4*)&bs[(k0 + kk) * 64 + tx * 4];
#pragma unroll
            for (int kk = 0; kk < 4; ++kk)
#pragma unroll
                for (int r = 0; r < 4; ++r) {
                    float xk = (kk == 0) ? av[r].x : (kk == 1) ? av[r].y
                             : (kk == 2) ? av[r].z : av[r].w;
                    acc[r][0] = __builtin_fmaf(xk, bv[kk].x, acc[r][0]);
                    acc[r][1] = __builtin_fmaf(xk, bv[kk].y, acc[r][1]);
                    acc[r][2] = __builtin_fmaf(xk, bv[kk].z, acc[r][2]);
                    acc[r][3] = __builtin_fmaf(xk, bv[kk].w, acc[r][3]);
                }
        }
        if (tt + 1 < nK) __syncthreads();
    }
#pragma unroll
    for (int r = 0; r < 4; ++r)
        *(float4*)&Cb[(size_t)(ty * 4 + r) * sC + tx * 4] =
            make_float4(acc[r][0], acc[r][1], acc[r][2], acc[r][3]);
}

// Stage A: Xw[row][j] = sum_w x[row][w] * FA[w][j], K-split 2.
__global__ __launch_bounds__(256) void gemmA(const float* __restrict__ x,
                                             const float* __restrict__ FA,
                                             float* __restrict__ Xw0,
                                             float* __restrict__ Xw1) {
    int rb = blockIdx.x >> 1, kh = blockIdx.x & 1;
    const float* Ab = x + (size_t)rb * 64 * 512 + kh * 256;
    const float* Bb = FA + (size_t)kh * 256 * 64;
    float* Cb = (kh ? Xw1 : Xw0) + (size_t)rb * 64 * 64;
    gemm64_core(Ab, 512, Bb, 64, Cb, 64, 4);
}

// Stage B: partial h-DFT. grid 512: i = bid>>3, ht = bid&7.
__global__ __launch_bounds__(256) void stageB(const float* __restrict__ Xw0,
                                              const float* __restrict__ Xw1,
                                              const float* __restrict__ GT,
                                              float* __restrict__ XFp) {
    __shared__ float xw[64][68];   // [hh][j]
    __shared__ float gt[64][68];   // [j][hh]
    int t = threadIdx.x;
    int i = blockIdx.x >> 3, ht = blockIdx.x & 7;
    int h0 = ht * 64;

#pragma unroll
    for (int p = 0; p < 4; ++p) {
        int flat = p * 1024 + t * 4;
        int hh = flat >> 6, c4 = flat & 63;
        float4 a = *(const float4*)&Xw0[((size_t)i * 512 + h0 + hh) * 64 + c4];
        float4 b = *(const float4*)&Xw1[((size_t)i * 512 + h0 + hh) * 64 + c4];
        *(float4*)&xw[hh][c4] = make_float4(a.x + b.x, a.y + b.y, a.z + b.z, a.w + b.w);
        float4 g = *(const float4*)&GT[(size_t)hh * 512 + h0 + c4];
        *(float4*)&gt[hh][c4] = g;
    }
    __syncthreads();

    int kx = t >> 3, kg = t & 7;   // ky = kg*4..kg*4+3
    float rr[4] = {0.f, 0.f, 0.f, 0.f};
    float ii[4] = {0.f, 0.f, 0.f, 0.f};
#pragma unroll 4
    for (int hh = 0; hh < 64; ++hh) {
        float cv = gt[kx][hh];
        float sv = gt[kx + 32][hh];          // = -sin
        float4 xr = *(const float4*)&xw[hh][kg * 4];
        float4 xi = *(const float4*)&xw[hh][32 + kg * 4];
        rr[0] = __builtin_fmaf(xr.x, cv, rr[0]); rr[0] = __builtin_fmaf(xi.x, -sv, rr[0]);
        rr[1] = __builtin_fmaf(xr.y, cv, rr[1]); rr[1] = __builtin_fmaf(xi.y, -sv, rr[1]);
        rr[2] = __builtin_fmaf(xr.z, cv, rr[2]); rr[2] = __builtin_fmaf(xi.z, -sv, rr[2]);
        rr[3] = __builtin_fmaf(xr.w, cv, rr[3]); rr[3] = __builtin_fmaf(xi.w, -sv, rr[3]);
        ii[0] = __builtin_fmaf(xi.x, cv, ii[0]); ii[0] = __builtin_fmaf(xr.x, sv, ii[0]);
        ii[1] = __builtin_fmaf(xi.y, cv, ii[1]); ii[1] = __builtin_fmaf(xr.y, sv, ii[1]);
        ii[2] = __builtin_fmaf(xi.z, cv, ii[2]); ii[2] = __builtin_fmaf(xr.z, sv, ii[2]);
        ii[3] = __builtin_fmaf(xi.w, cv, ii[3]); ii[3] = __builtin_fmaf(xr.w, sv, ii[3]);
    }
    size_t base = ((size_t)i * 8 + ht) * 2048;
    *(float4*)&XFp[base + t * 4]        = make_float4(rr[0], rr[1], rr[2], rr[3]);
    *(float4*)&XFp[base + 1024 + t * 4] = make_float4(ii[0], ii[1], ii[2], ii[3]);
}

// Stage C: partial channel mix, i split in 2. grid 512.
__global__ __launch_bounds__(256) void stageC(const float* __restrict__ XFp,
                                              const float* __restrict__ Wr,
                                              const float* __restrict__ Wi,
                                              float* __restrict__ Gp) {
    __shared__ float sxr[32][33];   // [ky][i']
    __shared__ float sxi[32][33];
    int t = threadIdx.x;
    int kx = blockIdx.x & 31, oc = (blockIdx.x >> 5) & 7, ic = blockIdx.x >> 8;
#pragma unroll
    for (int q = 0; q < 4; ++q) {
        int idx = q * 256 + t;               // 0..1023 = i'*32 + ky
        int ip = idx >> 5, ky = idx & 31;
        int i = ic * 32 + ip;
        float sr = 0.f, si = 0.f;
#pragma unroll
        for (int ht = 0; ht < 8; ++ht) {
            size_t base = ((size_t)i * 8 + ht) * 2048 + kx * 32 + ky;
            sr += XFp[base];
            si += XFp[base + 1024];
        }
        sxr[ky][ip] = sr;
        sxi[ky][ip] = si;
    }
    __syncthreads();
    int ky = t & 31, ol = t >> 5;
    int o = oc * 8 + ol;
    float lr = 0.f, li = 0.f;
#pragma unroll 4
    for (int ip = 0; ip < 32; ++ip) {
        float a = sxr[ky][ip];
        float b = sxi[ky][ip];
        size_t widx = ((size_t)(ic * 32 + ip) * 64 + o) * 1024 + kx * 32 + ky;
        float wrv = Wr[widx];
        float wiv = Wi[widx];
        lr = __builtin_fmaf(a, wrv, lr); lr = __builtin_fmaf(-b, wiv, lr);
        li = __builtin_fmaf(a, wiv, li); li = __builtin_fmaf(b, wrv, li);
    }
    size_t gidx = ((size_t)ic * 65536 + (size_t)o * 1024 + kx * 32 + ky) * 2;
    Gp[gidx]     = lr;
    Gp[gidx + 1] = li;
}

// Reduce the 2 i-partials and expand signs into G[o][m][j] (scaled).
__global__ __launch_bounds__(256) void reduceG(const float* __restrict__ Gp,
                                               float* __restrict__ G) {
    int idx = blockIdx.x * 256 + threadIdx.x;     // 0..65535 = o*1024+kx*32+ky
    int ky = idx & 31, kx = (idx >> 5) & 31, o = idx >> 10;
    float lr = Gp[(size_t)idx * 2]     + Gp[(size_t)(65536 + idx) * 2];
    float li = Gp[(size_t)idx * 2 + 1] + Gp[(size_t)(65536 + idx) * 2 + 1];
    float sc = ((ky == 0) ? 1.0f : 2.0f) * (1.0f / 262144.0f);
    lr *= sc; li *= sc;
    float* Go = G + (size_t)o * 4096;
    Go[kx * 64 + ky]             = lr;
    Go[(32 + kx) * 64 + 32 + ky] = lr;
    Go[kx * 64 + 32 + ky]        = li;
    Go[(32 + kx) * 64 + ky]      = -li;
}

// Stage D: Z[(o,h)][j] = sum_m F[h][m] * G[o][m][j]
__global__ __launch_bounds__(256) void gemmD(const float* __restrict__ F,
                                             const float* __restrict__ G,
                                             float* __restrict__ Z) {
    int o = blockIdx.x >> 3, ht = blockIdx.x & 7;
    const float* Ab = F + (size_t)ht * 64 * 64;
    const float* Bb = G + (size_t)o * 4096;
    float* Cb = Z + ((size_t)o * 512 + ht * 64) * 64;
    gemm64_core(Ab, 64, Bb, 64, Cb, 64, 1);
}

// Stage E: out[(o,h)][w] = sum_j Z[(o,h)][j] * GT[j][w]
__global__ __launch_bounds__(256) void gemmE(const float* __restrict__ Z,
                                             const float* __restrict__ GT,
                                             float* __restrict__ out) {
    int rb = blockIdx.x >> 3, cb = blockIdx.x & 7;
    const float* Ab = Z + (size_t)rb * 64 * 64;
    const float* Bb = GT + cb * 64;
    float* Cb = out + (size_t)rb * 64 * 512 + cb * 64;
    gemm64_core(Ab, 64, Bb, 512, Cb, 512, 1);
}

extern "C" void kernel_launch(void* const* d_in, const int* in_sizes, int n_in,
                              void* d_out, int out_size, void* d_ws, size_t ws_size,
                              hipStream_t stream) {
    const float* x  = (const float*)d_in[0];
    const float* Wr = (const float*)d_in[1];
    const float* Wi = (const float*)d_in[2];
    float* out = (float*)d_out;
    float* ws  = (float*)d_ws;

    float* F   = ws + OFF_F;
    float* FA  = ws + OFF_FA;
    float* GT  = ws + OFF_GT;
    float* Xw0 = ws + OFF_XW0;
    float* Xw1 = ws + OFF_XW1;
    float* XFp = ws + OFF_XFP;
    float* Gp  = ws + OFF_GP;
    float* G   = ws + OFF_G;
    float* Z   = ws + OFF_Z;

    build_table<<<128, 256, 0, stream>>>(F, FA, GT);
    gemmA<<<1024, 256, 0, stream>>>(x, FA, Xw0, Xw1);
    stageB<<<512, 256, 0, stream>>>(Xw0, Xw1, GT, XFp);
    stageC<<<512, 256, 0, stream>>>(XFp, Wr, Wi, Gp);
    reduceG<<<256, 256, 0, stream>>>(Gp, G);
    gemmD<<<512, 256, 0, stream>>>(F, G, Z);
    gemmE<<<4096, 256, 0, stream>>>(Z, GT, out);
}

// Round 6
// 74.661 us; speedup vs baseline: 1.3796x; 1.3796x over previous
//
#include <hip/hip_runtime.h>
#include <math.h>

#define IN_CH 64
#define OUT_CH 64
#define M1 32
#define M2 32
#define HH 512
#define WW 512

// ---------------- workspace layout (floats) ----------------
// F   : [512][64]  cols 0..31 = cos(2pi k h/512), cols 32..63 = sin(...)
// FA2 : [256][64]  folded stage-A table. col j<32: re, j>=32: im; mode k=kperm(j&31);
//                  value = cos(2pi k w'/512) (re) or -sin (im). kperm(q)= q<16 ? 2q : 2(q-16)+1.
// GE2 : [64][256]  folded stage-E table. row c: c<16 re k=2c; 16..31 im k=2(c-16);
//                  32..47 re k=2(c-32)+1; 48..63 im k=2(c-48)+1. cos (re) / -sin (im).
// GT  : [64][512]  row j<32: cos(2pi j t/512); row j>=32: -sin(...)   (stageB)
// Xw0 : [64][512][64]  partial folded w-DFT (w'-half 0), cols ky'-ordered
// Xw1 : same, w'-half 1
// XFp : [64 i][8 ht][2 reim][32 kx][32 ky']  partial h-DFT
// Gp  : [2 ic][64 o][32 kx][32 ky][2]  partial channel-mix (REAL ky order)
// G   : [64 o][64 m][64 j'] sign-expanded spectral matrix, cols parity-grouped for E-fold
// Z   : aliases Xw0  [64 o][512 h][64 j']
static const size_t OFF_F   = 0;
static const size_t OFF_FA2 = 32768;
static const size_t OFF_GE2 = 49152;
static const size_t OFF_GT  = 65536;
static const size_t OFF_XW0 = 98304;
static const size_t OFF_XW1 = OFF_XW0 + (size_t)64*512*64;
static const size_t OFF_XFP = OFF_XW1 + (size_t)64*512*64;
static const size_t OFF_GP  = OFF_XFP + (size_t)64*8*2048;
static const size_t OFF_G   = OFF_GP  + (size_t)2*65536*2;
static const size_t OFF_Z   = OFF_XW0;   // alias: Xw0 dead after stageB

__device__ __forceinline__ void gload16(const float* g, float* l) {
    __builtin_amdgcn_global_load_lds(
        (const __attribute__((address_space(1))) void*)g,
        (__attribute__((address_space(3))) void*)l, 16, 0, 0);
}

__global__ void build_table(float* __restrict__ F, float* __restrict__ FA2,
                            float* __restrict__ GE2, float* __restrict__ GT) {
    int idx = blockIdx.x * 256 + threadIdx.x;      // 0..32767
    const float c0 = 6.283185307179586f / 512.0f;
    {   // F + GT
        int w = idx >> 6, j = idx & 63, k = j & 31;
        int m = (k * w) & 511;
        float s, c;
        sincosf(c0 * (float)m, &s, &c);
        F[idx] = (j < 32) ? c : s;
        GT[(size_t)j * 512 + w] = (j < 32) ? c : -s;
    }
    if (idx < 16384) {   // FA2 [256][64]
        int wp = idx >> 6, j = idx & 63, q = j & 31;
        int k = (q < 16) ? 2 * q : 2 * (q - 16) + 1;
        int m = (k * wp) & 511;
        float s, c;
        sincosf(c0 * (float)m, &s, &c);
        FA2[idx] = (j < 32) ? c : -s;
    }
    if (idx < 16384) {   // GE2 [64][256]
        int cc = idx >> 8, wp = idx & 255;
        int base = cc & 15, parity = (cc >> 5) & 1, isIm = (cc >> 4) & 1;
        int k = 2 * base + parity;
        int m = (k * wp) & 511;
        float s, c;
        sincosf(c0 * (float)m, &s, &c);
        GE2[idx] = isIm ? -s : c;
    }
}

// Stage A folded: Xw[row][j'] over K=256 (e for even-k cols, o for odd-k cols).
// grid 1024: rb = bid>>1 (64-row tile), kh = bid&1 (w'-half of 128).
__global__ __launch_bounds__(256) void gemmA2(const float* __restrict__ x,
                                              const float* __restrict__ FA2,
                                              float* __restrict__ Xw0,
                                              float* __restrict__ Xw1) {
    __shared__ float xeo[8712];                     // xe @0 (64x68), xo @4360 (bank-shifted)
    __shared__ __align__(16) float bs[4096];        // FA2 tile, linear (gload_lds)
    int t = threadIdx.x, tx = t & 15, ty = t >> 4;
    int rb = blockIdx.x >> 1, kh = blockIdx.x & 1;
    int rowBase = rb * 64;
    float acc[4][4] = {};

    for (int tt = 0; tt < 2; ++tt) {
        int w0 = kh * 128 + tt * 64;
#pragma unroll
        for (int p = 0; p < 4; ++p) {
            int flat = p * 1024 + t * 4;
            int rl = flat >> 6, c4 = flat & 63;
            const float* xr = &x[(size_t)(rowBase + rl) * 512 + w0 + c4];
            float4 a = *(const float4*)xr;
            float4 b = *(const float4*)(xr + 256);
            *(float4*)&xeo[rl * 68 + c4] =
                make_float4(a.x + b.x, a.y + b.y, a.z + b.z, a.w + b.w);
            *(float4*)&xeo[4360 + rl * 68 + c4] =
                make_float4(a.x - b.x, a.y - b.y, a.z - b.z, a.w - b.w);
            gload16(FA2 + (size_t)(w0 + rl) * 64 + c4, &bs[flat]);
        }
        __syncthreads();
        const float* xsb = &xeo[(tx & 4) ? 4360 : 0];   // cols 16..31,48..63 -> odd k -> o
#pragma unroll 4
        for (int k0 = 0; k0 < 64; k0 += 4) {
            float4 av[4], bv[4];
#pragma unroll
            for (int r = 0; r < 4; ++r)
                av[r] = *(const float4*)&xsb[(ty * 4 + r) * 68 + k0];
#pragma unroll
            for (int kk = 0; kk < 4; ++kk)
                bv[kk] = *(const float4*)&bs[(k0 + kk) * 64 + tx * 4];
#pragma unroll
            for (int kk = 0; kk < 4; ++kk)
#pragma unroll
                for (int r = 0; r < 4; ++r) {
                    float xk = (kk == 0) ? av[r].x : (kk == 1) ? av[r].y
                             : (kk == 2) ? av[r].z : av[r].w;
                    acc[r][0] = __builtin_fmaf(xk, bv[kk].x, acc[r][0]);
                    acc[r][1] = __builtin_fmaf(xk, bv[kk].y, acc[r][1]);
                    acc[r][2] = __builtin_fmaf(xk, bv[kk].z, acc[r][2]);
                    acc[r][3] = __builtin_fmaf(xk, bv[kk].w, acc[r][3]);
                }
        }
        if (tt == 0) __syncthreads();
    }
    float* Cb = (kh ? Xw1 : Xw0) + (size_t)rowBase * 64;
#pragma unroll
    for (int r = 0; r < 4; ++r)
        *(float4*)&Cb[(size_t)(ty * 4 + r) * 64 + tx * 4] =
            make_float4(acc[r][0], acc[r][1], acc[r][2], acc[r][3]);
}

// Stage B: partial h-DFT (cols are ky'-agnostic). grid 512: i = bid>>3, ht = bid&7.
__global__ __launch_bounds__(256) void stageB(const float* __restrict__ Xw0,
                                              const float* __restrict__ Xw1,
                                              const float* __restrict__ GT,
                                              float* __restrict__ XFp) {
    __shared__ float xw[64][68];   // [hh][j]
    __shared__ float gt[64][68];   // [j][hh]
    int t = threadIdx.x;
    int i = blockIdx.x >> 3, ht = blockIdx.x & 7;
    int h0 = ht * 64;

#pragma unroll
    for (int p = 0; p < 4; ++p) {
        int flat = p * 1024 + t * 4;
        int hh = flat >> 6, c4 = flat & 63;
        float4 a = *(const float4*)&Xw0[((size_t)i * 512 + h0 + hh) * 64 + c4];
        float4 b = *(const float4*)&Xw1[((size_t)i * 512 + h0 + hh) * 64 + c4];
        *(float4*)&xw[hh][c4] = make_float4(a.x + b.x, a.y + b.y, a.z + b.z, a.w + b.w);
        float4 g = *(const float4*)&GT[(size_t)hh * 512 + h0 + c4];
        *(float4*)&gt[hh][c4] = g;
    }
    __syncthreads();

    int kx = t >> 3, kg = t & 7;
    float rr[4] = {0.f, 0.f, 0.f, 0.f};
    float ii[4] = {0.f, 0.f, 0.f, 0.f};
#pragma unroll 4
    for (int hh = 0; hh < 64; ++hh) {
        float cv = gt[kx][hh];
        float sv = gt[kx + 32][hh];          // = -sin
        float4 xr = *(const float4*)&xw[hh][kg * 4];
        float4 xi = *(const float4*)&xw[hh][32 + kg * 4];
        rr[0] = __builtin_fmaf(xr.x, cv, rr[0]); rr[0] = __builtin_fmaf(xi.x, -sv, rr[0]);
        rr[1] = __builtin_fmaf(xr.y, cv, rr[1]); rr[1] = __builtin_fmaf(xi.y, -sv, rr[1]);
        rr[2] = __builtin_fmaf(xr.z, cv, rr[2]); rr[2] = __builtin_fmaf(xi.z, -sv, rr[2]);
        rr[3] = __builtin_fmaf(xr.w, cv, rr[3]); rr[3] = __builtin_fmaf(xi.w, -sv, rr[3]);
        ii[0] = __builtin_fmaf(xi.x, cv, ii[0]); ii[0] = __builtin_fmaf(xr.x, sv, ii[0]);
        ii[1] = __builtin_fmaf(xi.y, cv, ii[1]); ii[1] = __builtin_fmaf(xr.y, sv, ii[1]);
        ii[2] = __builtin_fmaf(xi.z, cv, ii[2]); ii[2] = __builtin_fmaf(xr.z, sv, ii[2]);
        ii[3] = __builtin_fmaf(xi.w, cv, ii[3]); ii[3] = __builtin_fmaf(xr.w, sv, ii[3]);
    }
    size_t base = ((size_t)i * 8 + ht) * 2048;
    *(float4*)&XFp[base + t * 4]        = make_float4(rr[0], rr[1], rr[2], rr[3]);
    *(float4*)&XFp[base + 1024 + t * 4] = make_float4(ii[0], ii[1], ii[2], ii[3]);
}

// Stage C: partial channel mix, i split in 2. grid 512. XFp cols are ky'-ordered;
// threads own REAL ky (coalesced W) and read the permuted LDS row (conflict-free).
__global__ __launch_bounds__(256) void stageC(const float* __restrict__ XFp,
                                              const float* __restrict__ Wr,
                                              const float* __restrict__ Wi,
                                              float* __restrict__ Gp) {
    __shared__ float sxr[32][33];   // [ky'][i']
    __shared__ float sxi[32][33];
    int t = threadIdx.x;
    int kx = blockIdx.x & 31, oc = (blockIdx.x >> 5) & 7, ic = blockIdx.x >> 8;
#pragma unroll
    for (int q = 0; q < 4; ++q) {
        int idx = q * 256 + t;               // 0..1023 = i'*32 + ky'(storage)
        int ip = idx >> 5, kys = idx & 31;
        int i = ic * 32 + ip;
        float sr = 0.f, si = 0.f;
#pragma unroll
        for (int ht = 0; ht < 8; ++ht) {
            size_t base = ((size_t)i * 8 + ht) * 2048 + kx * 32 + kys;
            sr += XFp[base];
            si += XFp[base + 1024];
        }
        sxr[kys][ip] = sr;
        sxi[kys][ip] = si;
    }
    __syncthreads();
    int ky = t & 31, ol = t >> 5;            // REAL ky
    int kyp = (ky & 1) ? 16 + (ky >> 1) : (ky >> 1);
    int o = oc * 8 + ol;
    float lr = 0.f, li = 0.f;
#pragma unroll 4
    for (int ip = 0; ip < 32; ++ip) {
        float a = sxr[kyp][ip];
        float b = sxi[kyp][ip];
        size_t widx = ((size_t)(ic * 32 + ip) * 64 + o) * 1024 + kx * 32 + ky;
        float wrv = Wr[widx];
        float wiv = Wi[widx];
        lr = __builtin_fmaf(a, wrv, lr); lr = __builtin_fmaf(-b, wiv, lr);
        li = __builtin_fmaf(a, wiv, li); li = __builtin_fmaf(b, wrv, li);
    }
    size_t gidx = ((size_t)ic * 65536 + (size_t)o * 1024 + kx * 32 + ky) * 2;
    Gp[gidx]     = lr;
    Gp[gidx + 1] = li;
}

// Reduce partials, scale, sign-expand into G[o][m][j'] with PARITY-GROUPED j' cols:
// col(re, k) = (k&1)*32 + (k>>1); col(im, k) = (k&1)*32 + 16 + (k>>1).
__global__ __launch_bounds__(256) void reduceG(const float* __restrict__ Gp,
                                               float* __restrict__ G) {
    int idx = blockIdx.x * 256 + threadIdx.x;     // 0..65535 = o*1024+kx*32+ky (REAL ky)
    int ky = idx & 31, kx = (idx >> 5) & 31, o = idx >> 10;
    float lr = Gp[(size_t)idx * 2]     + Gp[(size_t)(65536 + idx) * 2];
    float li = Gp[(size_t)idx * 2 + 1] + Gp[(size_t)(65536 + idx) * 2 + 1];
    float sc = ((ky == 0) ? 1.0f : 2.0f) * (1.0f / 262144.0f);
    lr *= sc; li *= sc;
    int p = ky & 1, q = ky >> 1;
    int colR = p * 32 + q, colI = p * 32 + 16 + q;
    float* Go = G + (size_t)o * 4096;
    Go[kx * 64 + colR]        = lr;
    Go[(32 + kx) * 64 + colR] = -li;
    Go[kx * 64 + colI]        = li;
    Go[(32 + kx) * 64 + colI] = lr;
}

// Unified 64-wide GEMM tile with source-swizzled A staging (conflict-free reads).
__device__ __forceinline__ void gemm64_core(const float* __restrict__ Ab, int sA,
                                            const float* __restrict__ Bb, int sB,
                                            float* __restrict__ Cb, int sC, int nK) {
    __shared__ __align__(16) float as[4096];   // swizzled: (row, c^((row>>2)&3))
    __shared__ __align__(16) float bs[4096];   // linear
    int t = threadIdx.x, tx = t & 15, ty = t >> 4;
    float acc[4][4] = {};
    int sw = (ty & 3) << 2;
    for (int tt = 0; tt < nK; ++tt) {
#pragma unroll
        for (int p = 0; p < 4; ++p) {
            int flat = p * 1024 + t * 4;
            int s16 = flat >> 2;
            int row = s16 >> 4, cp = s16 & 15;
            int cg = cp ^ ((row >> 2) & 3);
            gload16(Ab + (size_t)row * sA + tt * 64 + cg * 4, &as[flat]);
            int brow = flat >> 6, bcol = flat & 63;
            gload16(Bb + (size_t)(tt * 64 + brow) * sB + bcol, &bs[flat]);
        }
        __syncthreads();
#pragma unroll 4
        for (int k0 = 0; k0 < 64; k0 += 4) {
            int ka = k0 ^ sw;
            float4 av[4], bv[4];
#pragma unroll
            for (int r = 0; r < 4; ++r)
                av[r] = *(const float4*)&as[(ty * 4 + r) * 64 + ka];
#pragma unroll
            for (int kk = 0; kk < 4; ++kk)
                bv[kk] = *(const float4*)&bs[(k0 + kk) * 64 + tx * 4];
#pragma unroll
            for (int kk = 0; kk < 4; ++kk)
#pragma unroll
                for (int r = 0; r < 4; ++r) {
                    float xk = (kk == 0) ? av[r].x : (kk == 1) ? av[r].y
                             : (kk == 2) ? av[r].z : av[r].w;
                    acc[r][0] = __builtin_fmaf(xk, bv[kk].x, acc[r][0]);
                    acc[r][1] = __builtin_fmaf(xk, bv[kk].y, acc[r][1]);
                    acc[r][2] = __builtin_fmaf(xk, bv[kk].z, acc[r][2]);
                    acc[r][3] = __builtin_fmaf(xk, bv[kk].w, acc[r][3]);
                }
        }
        if (tt + 1 < nK) __syncthreads();
    }
#pragma unroll
    for (int r = 0; r < 4; ++r)
        *(float4*)&Cb[(size_t)(ty * 4 + r) * sC + tx * 4] =
            make_float4(acc[r][0], acc[r][1], acc[r][2], acc[r][3]);
}

// Stage D: Z[(o,h)][j'] = sum_m F[h][m] * G[o][m][j']
__global__ __launch_bounds__(256) void gemmD(const float* __restrict__ F,
                                             const float* __restrict__ G,
                                             float* __restrict__ Z) {
    int o = blockIdx.x >> 3, ht = blockIdx.x & 7;
    const float* Ab = F + (size_t)ht * 64 * 64;
    const float* Bb = G + (size_t)o * 4096;
    float* Cb = Z + ((size_t)o * 512 + ht * 64) * 64;
    gemm64_core(Ab, 64, Bb, 64, Cb, 64, 1);
}

// Stage E folded: P = Z'[:, 0..31] x GE2[0..31], Q = Z'[:, 32..63] x GE2[32..63];
// out[w'] = P+Q, out[w'+256] = P-Q. grid 2048: rb = bid>>2, cb = bid&3 (w'-tile).
__global__ __launch_bounds__(256) void gemmE2(const float* __restrict__ Zp,
                                              const float* __restrict__ GE2,
                                              float* __restrict__ out) {
    __shared__ __align__(16) float zs[4096];   // swizzled A
    __shared__ __align__(16) float gs[4096];   // linear B
    int t = threadIdx.x, tx = t & 15, ty = t >> 4;
    int rb = blockIdx.x >> 2, cb = blockIdx.x & 3;
    int rowBase = rb * 64, w0 = cb * 64;
    int sw = (ty & 3) << 2;
#pragma unroll
    for (int p = 0; p < 4; ++p) {
        int flat = p * 1024 + t * 4;
        int s16 = flat >> 2;
        int row = s16 >> 4, cp = s16 & 15;
        int cg = cp ^ ((row >> 2) & 3);
        gload16(Zp + (size_t)(rowBase + row) * 64 + cg * 4, &zs[flat]);
        int brow = flat >> 6, bcol = flat & 63;
        gload16(GE2 + (size_t)brow * 256 + w0 + bcol, &gs[flat]);
    }
    __syncthreads();
    float pa[4][4] = {}, pb[4][4] = {};
#pragma unroll 4
    for (int k0 = 0; k0 < 32; k0 += 4) {
        int kae = k0 ^ sw, kao = 32 + (k0 ^ sw);
        float4 av[4], bv[4], aw[4], bw[4];
#pragma unroll
        for (int r = 0; r < 4; ++r) {
            av[r] = *(const float4*)&zs[(ty * 4 + r) * 64 + kae];
            aw[r] = *(const float4*)&zs[(ty * 4 + r) * 64 + kao];
        }
#pragma unroll
        for (int kk = 0; kk < 4; ++kk) {
            bv[kk] = *(const float4*)&gs[(k0 + kk) * 64 + tx * 4];
            bw[kk] = *(const float4*)&gs[(32 + k0 + kk) * 64 + tx * 4];
        }
#pragma unroll
        for (int kk = 0; kk < 4; ++kk)
#pragma unroll
            for (int r = 0; r < 4; ++r) {
                float xe = (kk == 0) ? av[r].x : (kk == 1) ? av[r].y
                         : (kk == 2) ? av[r].z : av[r].w;
                float xo = (kk == 0) ? aw[r].x : (kk == 1) ? aw[r].y
                         : (kk == 2) ? aw[r].z : aw[r].w;
                pa[r][0] = __builtin_fmaf(xe, bv[kk].x, pa[r][0]);
                pa[r][1] = __builtin_fmaf(xe, bv[kk].y, pa[r][1]);
                pa[r][2] = __builtin_fmaf(xe, bv[kk].z, pa[r][2]);
                pa[r][3] = __builtin_fmaf(xe, bv[kk].w, pa[r][3]);
                pb[r][0] = __builtin_fmaf(xo, bw[kk].x, pb[r][0]);
                pb[r][1] = __builtin_fmaf(xo, bw[kk].y, pb[r][1]);
                pb[r][2] = __builtin_fmaf(xo, bw[kk].z, pb[r][2]);
                pb[r][3] = __builtin_fmaf(xo, bw[kk].w, pb[r][3]);
            }
    }
#pragma unroll
    for (int r = 0; r < 4; ++r) {
        float* orow = out + (size_t)(rowBase + ty * 4 + r) * 512;
        *(float4*)&orow[w0 + tx * 4] =
            make_float4(pa[r][0] + pb[r][0], pa[r][1] + pb[r][1],
                        pa[r][2] + pb[r][2], pa[r][3] + pb[r][3]);
        *(float4*)&orow[256 + w0 + tx * 4] =
            make_float4(pa[r][0] - pb[r][0], pa[r][1] - pb[r][1],
                        pa[r][2] - pb[r][2], pa[r][3] - pb[r][3]);
    }
}

extern "C" void kernel_launch(void* const* d_in, const int* in_sizes, int n_in,
                              void* d_out, int out_size, void* d_ws, size_t ws_size,
                              hipStream_t stream) {
    const float* x  = (const float*)d_in[0];
    const float* Wr = (const float*)d_in[1];
    const float* Wi = (const float*)d_in[2];
    float* out = (float*)d_out;
    float* ws  = (float*)d_ws;

    float* F   = ws + OFF_F;
    float* FA2 = ws + OFF_FA2;
    float* GE2 = ws + OFF_GE2;
    float* GT  = ws + OFF_GT;
    float* Xw0 = ws + OFF_XW0;
    float* Xw1 = ws + OFF_XW1;
    float* XFp = ws + OFF_XFP;
    float* Gp  = ws + OFF_GP;
    float* G   = ws + OFF_G;
    float* Z   = ws + OFF_Z;

    build_table<<<128, 256, 0, stream>>>(F, FA2, GE2, GT);
    gemmA2<<<1024, 256, 0, stream>>>(x, FA2, Xw0, Xw1);
    stageB<<<512, 256, 0, stream>>>(Xw0, Xw1, GT, XFp);
    stageC<<<512, 256, 0, stream>>>(XFp, Wr, Wi, Gp);
    reduceG<<<256, 256, 0, stream>>>(Gp, G);
    gemmD<<<512, 256, 0, stream>>>(F, G, Z);
    gemmE2<<<2048, 256, 0, stream>>>(Z, GE2, out);
}

// Round 7
// 67.854 us; speedup vs baseline: 1.5180x; 1.1003x over previous
//
#include <hip/hip_runtime.h>
#include <math.h>

#define IN_CH 64
#define OUT_CH 64
#define M1 32
#define M2 32
#define HH 512
#define WW 512

// ---------------- workspace layout (floats) ----------------
// F   : [512][64]  cols 0..31 = cos(2pi k h/512), cols 32..63 = sin(...)
// FA2 : [256][64]  folded stage-A table. col j<32: re, j>=32: im; mode k=kperm(j&31);
//                  value = cos(2pi k w'/512) (re) or -sin (im). kperm(q)= q<16 ? 2q : 2(q-16)+1.
// GE2 : [64][256]  folded stage-E table. row c: c<16 re k=2c; 16..31 im k=2(c-16);
//                  32..47 re k=2(c-32)+1; 48..63 im k=2(c-48)+1. cos (re) / -sin (im).
// GT  : [64][512]  row j<32: cos(2pi j t/512); row j>=32: -sin(...)
// XFp : [64 i][8 ht][2 reim][32 kx][32 ky']  partial h-DFT
// Gp  : [2 ic][64 o][32 kx][32 ky][2]  partial channel-mix (REAL ky order)
static const size_t OFF_F   = 0;
static const size_t OFF_FA2 = 32768;
static const size_t OFF_GE2 = 49152;
static const size_t OFF_GT  = 65536;
static const size_t OFF_XFP = 98304;
static const size_t OFF_GP  = OFF_XFP + (size_t)64*8*2048;

__device__ __forceinline__ void gload16(const float* g, float* l) {
    __builtin_amdgcn_global_load_lds(
        (const __attribute__((address_space(1))) void*)g,
        (__attribute__((address_space(3))) void*)l, 16, 0, 0);
}

__global__ void build_table(float* __restrict__ F, float* __restrict__ FA2,
                            float* __restrict__ GE2, float* __restrict__ GT) {
    int idx = blockIdx.x * 256 + threadIdx.x;      // 0..32767
    const float c0 = 6.283185307179586f / 512.0f;
    {   // F + GT
        int w = idx >> 6, j = idx & 63, k = j & 31;
        int m = (k * w) & 511;
        float s, c;
        sincosf(c0 * (float)m, &s, &c);
        F[idx] = (j < 32) ? c : s;
        GT[(size_t)j * 512 + w] = (j < 32) ? c : -s;
    }
    if (idx < 16384) {   // FA2 [256][64]
        int wp = idx >> 6, j = idx & 63, q = j & 31;
        int k = (q < 16) ? 2 * q : 2 * (q - 16) + 1;
        int m = (k * wp) & 511;
        float s, c;
        sincosf(c0 * (float)m, &s, &c);
        FA2[idx] = (j < 32) ? c : -s;
    }
    if (idx < 16384) {   // GE2 [64][256]
        int cc = idx >> 8, wp = idx & 255;
        int base = cc & 15, parity = (cc >> 5) & 1, isIm = (cc >> 4) & 1;
        int k = 2 * base + parity;
        int m = (k * wp) & 511;
        float s, c;
        sincosf(c0 * (float)m, &s, &c);
        GE2[idx] = isIm ? -s : c;
    }
}

// Fused A+B. grid 512: i = bid>>3, ht = bid&7 (64 h-rows).
// Phase A: Xw[h][j'] = sum_{w'} xeo[h][w'] * FA2[w'][j']  (K=256, w'-parity folded)
// Phase B: XFp[i][ht][re/im][kx][ky'] = sum_hh Xw[hh][ky'] * e^{-2pi i kx h/512}
__global__ __launch_bounds__(256) void fusedAB(const float* __restrict__ x,
                                               const float* __restrict__ FA2,
                                               const float* __restrict__ GT,
                                               float* __restrict__ XFp) {
    __shared__ __align__(16) float xeo[8712];   // xe [64][68] @0; xo @4360; later xw [64][68] @0
    __shared__ __align__(16) float bs[4352];    // FA2 tiles linear [64][64]; later gt [64][68]
    int t = threadIdx.x, tx = t & 15, ty = t >> 4;
    int i = blockIdx.x >> 3, ht = blockIdx.x & 7;
    int h0 = ht * 64;
    float acc[4][4] = {};

    for (int tt = 0; tt < 4; ++tt) {
        int w0 = tt * 64;
#pragma unroll
        for (int p = 0; p < 4; ++p) {
            int flat = p * 1024 + t * 4;
            int rl = flat >> 6, c4 = flat & 63;
            const float* xr = &x[((size_t)i * 512 + h0 + rl) * 512 + w0 + c4];
            float4 a = *(const float4*)xr;
            float4 b = *(const float4*)(xr + 256);
            *(float4*)&xeo[rl * 68 + c4] =
                make_float4(a.x + b.x, a.y + b.y, a.z + b.z, a.w + b.w);
            *(float4*)&xeo[4360 + rl * 68 + c4] =
                make_float4(a.x - b.x, a.y - b.y, a.z - b.z, a.w - b.w);
            gload16(FA2 + (size_t)(w0 + rl) * 64 + c4, &bs[flat]);
        }
        __syncthreads();
        const float* xsb = &xeo[(tx & 4) ? 4360 : 0];   // cols 16..31,48..63: odd-k -> o
#pragma unroll 4
        for (int k0 = 0; k0 < 64; k0 += 4) {
            float4 av[4], bv[4];
#pragma unroll
            for (int r = 0; r < 4; ++r)
                av[r] = *(const float4*)&xsb[(ty * 4 + r) * 68 + k0];
#pragma unroll
            for (int kk = 0; kk < 4; ++kk)
                bv[kk] = *(const float4*)&bs[(k0 + kk) * 64 + tx * 4];
#pragma unroll
            for (int kk = 0; kk < 4; ++kk)
#pragma unroll
                for (int r = 0; r < 4; ++r) {
                    float xk = (kk == 0) ? av[r].x : (kk == 1) ? av[r].y
                             : (kk == 2) ? av[r].z : av[r].w;
                    acc[r][0] = __builtin_fmaf(xk, bv[kk].x, acc[r][0]);
                    acc[r][1] = __builtin_fmaf(xk, bv[kk].y, acc[r][1]);
                    acc[r][2] = __builtin_fmaf(xk, bv[kk].z, acc[r][2]);
                    acc[r][3] = __builtin_fmaf(xk, bv[kk].w, acc[r][3]);
                }
        }
        __syncthreads();
    }

    // store Xw tile into xeo[0..] ([64][68]) and stage gt ([64][68]) into bs
#pragma unroll
    for (int r = 0; r < 4; ++r)
        *(float4*)&xeo[(ty * 4 + r) * 68 + tx * 4] =
            make_float4(acc[r][0], acc[r][1], acc[r][2], acc[r][3]);
#pragma unroll
    for (int p = 0; p < 4; ++p) {
        int flat = p * 1024 + t * 4;
        int j = flat >> 6, c4 = flat & 63;
        float4 g = *(const float4*)&GT[(size_t)j * 512 + h0 + c4];
        *(float4*)&bs[j * 68 + c4] = g;
    }
    __syncthreads();

    // Phase B
    int kx = t >> 3, kg = t & 7;
    float rr[4] = {0.f, 0.f, 0.f, 0.f};
    float ii[4] = {0.f, 0.f, 0.f, 0.f};
#pragma unroll 4
    for (int hh = 0; hh < 64; ++hh) {
        float cv = bs[kx * 68 + hh];
        float sv = bs[(kx + 32) * 68 + hh];          // = -sin
        float4 xr4 = *(const float4*)&xeo[hh * 68 + kg * 4];
        float4 xi4 = *(const float4*)&xeo[hh * 68 + 32 + kg * 4];
        rr[0] = __builtin_fmaf(xr4.x, cv, rr[0]); rr[0] = __builtin_fmaf(xi4.x, -sv, rr[0]);
        rr[1] = __builtin_fmaf(xr4.y, cv, rr[1]); rr[1] = __builtin_fmaf(xi4.y, -sv, rr[1]);
        rr[2] = __builtin_fmaf(xr4.z, cv, rr[2]); rr[2] = __builtin_fmaf(xi4.z, -sv, rr[2]);
        rr[3] = __builtin_fmaf(xr4.w, cv, rr[3]); rr[3] = __builtin_fmaf(xi4.w, -sv, rr[3]);
        ii[0] = __builtin_fmaf(xi4.x, cv, ii[0]); ii[0] = __builtin_fmaf(xr4.x, sv, ii[0]);
        ii[1] = __builtin_fmaf(xi4.y, cv, ii[1]); ii[1] = __builtin_fmaf(xr4.y, sv, ii[1]);
        ii[2] = __builtin_fmaf(xi4.z, cv, ii[2]); ii[2] = __builtin_fmaf(xr4.z, sv, ii[2]);
        ii[3] = __builtin_fmaf(xi4.w, cv, ii[3]); ii[3] = __builtin_fmaf(xr4.w, sv, ii[3]);
    }
    size_t base = ((size_t)i * 8 + ht) * 2048;
    *(float4*)&XFp[base + t * 4]        = make_float4(rr[0], rr[1], rr[2], rr[3]);
    *(float4*)&XFp[base + 1024 + t * 4] = make_float4(ii[0], ii[1], ii[2], ii[3]);
}

// Stage C: partial channel mix, i split in 2. grid 512. (unchanged from R6)
__global__ __launch_bounds__(256) void stageC(const float* __restrict__ XFp,
                                              const float* __restrict__ Wr,
                                              const float* __restrict__ Wi,
                                              float* __restrict__ Gp) {
    __shared__ float sxr[32][33];   // [ky'][i']
    __shared__ float sxi[32][33];
    int t = threadIdx.x;
    int kx = blockIdx.x & 31, oc = (blockIdx.x >> 5) & 7, ic = blockIdx.x >> 8;
#pragma unroll
    for (int q = 0; q < 4; ++q) {
        int idx = q * 256 + t;               // 0..1023 = i'*32 + ky'(storage)
        int ip = idx >> 5, kys = idx & 31;
        int i = ic * 32 + ip;
        float sr = 0.f, si = 0.f;
#pragma unroll
        for (int ht = 0; ht < 8; ++ht) {
            size_t base = ((size_t)i * 8 + ht) * 2048 + kx * 32 + kys;
            sr += XFp[base];
            si += XFp[base + 1024];
        }
        sxr[kys][ip] = sr;
        sxi[kys][ip] = si;
    }
    __syncthreads();
    int ky = t & 31, ol = t >> 5;            // REAL ky
    int kyp = (ky & 1) ? 16 + (ky >> 1) : (ky >> 1);
    int o = oc * 8 + ol;
    float lr = 0.f, li = 0.f;
#pragma unroll 4
    for (int ip = 0; ip < 32; ++ip) {
        float a = sxr[kyp][ip];
        float b = sxi[kyp][ip];
        size_t widx = ((size_t)(ic * 32 + ip) * 64 + o) * 1024 + kx * 32 + ky;
        float wrv = Wr[widx];
        float wiv = Wi[widx];
        lr = __builtin_fmaf(a, wrv, lr); lr = __builtin_fmaf(-b, wiv, lr);
        li = __builtin_fmaf(a, wiv, li); li = __builtin_fmaf(b, wrv, li);
    }
    size_t gidx = ((size_t)ic * 65536 + (size_t)o * 1024 + kx * 32 + ky) * 2;
    Gp[gidx]     = lr;
    Gp[gidx + 1] = li;
}

// Fused (reduceG +) D + E. grid 512: o = bid>>3, ht = bid&7.
// D: Z[h][j'] = sum_m F[h][m] * G[o][m][j']  (G built in LDS from Gp, parity-grouped cols)
// E: P = Z[:,0..31] x GE2[0..31], Q = Z[:,32..63] x GE2[32..63]; out[w']=P+Q, out[w'+256]=P-Q
__global__ __launch_bounds__(256) void fusedDE(const float* __restrict__ Fc,
                                               const float* __restrict__ Gp,
                                               const float* __restrict__ GE2,
                                               float* __restrict__ out) {
    __shared__ __align__(16) float as[4096];   // F-tile (src-swizzled), then Z (XOR-swizzled)
    __shared__ __align__(16) float bs[4096];   // G [64m][64j'], then GE2 tiles
    int t = threadIdx.x, tx = t & 15, ty = t >> 4;
    int o = blockIdx.x >> 3, ht = blockIdx.x & 7;
    int sw = (ty & 3) << 2;

    // build G[o] into bs (reduce 2 i-partials, scale, sign-expand, parity-grouped cols)
    const float2* gp2 = (const float2*)Gp;
#pragma unroll
    for (int q = 0; q < 4; ++q) {
        int iq = q * 256 + t;                 // 0..1023 = kx*32+ky (REAL ky)
        int ky = iq & 31, kx = iq >> 5;
        float2 g0 = gp2[(size_t)o * 1024 + iq];
        float2 g1 = gp2[(size_t)65536 + (size_t)o * 1024 + iq];
        float sc = ((ky == 0) ? 1.0f : 2.0f) * (1.0f / 262144.0f);
        float lr = (g0.x + g1.x) * sc;
        float li = (g0.y + g1.y) * sc;
        int pp = ky & 1, qq = ky >> 1;
        int colR = pp * 32 + qq, colI = pp * 32 + 16 + qq;
        bs[kx * 64 + colR]        = lr;
        bs[(32 + kx) * 64 + colR] = -li;
        bs[kx * 64 + colI]        = li;
        bs[(32 + kx) * 64 + colI] = lr;
    }
    // stage F-tile into as (source-swizzled for conflict-free A-side reads)
#pragma unroll
    for (int p = 0; p < 4; ++p) {
        int flat = p * 1024 + t * 4;
        int s16 = flat >> 2;
        int row = s16 >> 4, cp = s16 & 15;
        int cg = cp ^ ((row >> 2) & 3);
        gload16(Fc + (size_t)(ht * 64 + row) * 64 + cg * 4, &as[flat]);
    }
    __syncthreads();

    // D inner: K=64
    float acc[4][4] = {};
#pragma unroll 4
    for (int k0 = 0; k0 < 64; k0 += 4) {
        int ka = k0 ^ sw;
        float4 av[4], bv[4];
#pragma unroll
        for (int r = 0; r < 4; ++r)
            av[r] = *(const float4*)&as[(ty * 4 + r) * 64 + ka];
#pragma unroll
        for (int kk = 0; kk < 4; ++kk)
            bv[kk] = *(const float4*)&bs[(k0 + kk) * 64 + tx * 4];
#pragma unroll
        for (int kk = 0; kk < 4; ++kk)
#pragma unroll
            for (int r = 0; r < 4; ++r) {
                float xk = (kk == 0) ? av[r].x : (kk == 1) ? av[r].y
                         : (kk == 2) ? av[r].z : av[r].w;
                acc[r][0] = __builtin_fmaf(xk, bv[kk].x, acc[r][0]);
                acc[r][1] = __builtin_fmaf(xk, bv[kk].y, acc[r][1]);
                acc[r][2] = __builtin_fmaf(xk, bv[kk].z, acc[r][2]);
                acc[r][3] = __builtin_fmaf(xk, bv[kk].w, acc[r][3]);
            }
    }
    __syncthreads();

    // store Z into as with XOR swizzle (matches E's read pattern)
#pragma unroll
    for (int r = 0; r < 4; ++r) {
        int row = ty * 4 + r;
        int cg = tx ^ ((row >> 2) & 3);
        *(float4*)&as[row * 64 + cg * 4] =
            make_float4(acc[r][0], acc[r][1], acc[r][2], acc[r][3]);
    }

    // E loop over 4 w'-tiles of 64
    for (int cb = 0; cb < 4; ++cb) {
        __syncthreads();   // prior bs readers done (D inner / previous E inner); zs store visible
#pragma unroll
        for (int p = 0; p < 4; ++p) {
            int flat = p * 1024 + t * 4;
            int brow = flat >> 6, bcol = flat & 63;
            gload16(GE2 + (size_t)brow * 256 + cb * 64 + bcol, &bs[flat]);
        }
        __syncthreads();
        float pa[4][4] = {}, pb[4][4] = {};
#pragma unroll 4
        for (int k0 = 0; k0 < 32; k0 += 4) {
            int kae = k0 ^ sw, kao = 32 + (k0 ^ sw);
            float4 av[4], bv[4], aw[4], bw[4];
#pragma unroll
            for (int r = 0; r < 4; ++r) {
                av[r] = *(const float4*)&as[(ty * 4 + r) * 64 + kae];
                aw[r] = *(const float4*)&as[(ty * 4 + r) * 64 + kao];
            }
#pragma unroll
            for (int kk = 0; kk < 4; ++kk) {
                bv[kk] = *(const float4*)&bs[(k0 + kk) * 64 + tx * 4];
                bw[kk] = *(const float4*)&bs[(32 + k0 + kk) * 64 + tx * 4];
            }
#pragma unroll
            for (int kk = 0; kk < 4; ++kk)
#pragma unroll
                for (int r = 0; r < 4; ++r) {
                    float xe = (kk == 0) ? av[r].x : (kk == 1) ? av[r].y
                             : (kk == 2) ? av[r].z : av[r].w;
                    float xo = (kk == 0) ? aw[r].x : (kk == 1) ? aw[r].y
                             : (kk == 2) ? aw[r].z : aw[r].w;
                    pa[r][0] = __builtin_fmaf(xe, bv[kk].x, pa[r][0]);
                    pa[r][1] = __builtin_fmaf(xe, bv[kk].y, pa[r][1]);
                    pa[r][2] = __builtin_fmaf(xe, bv[kk].z, pa[r][2]);
                    pa[r][3] = __builtin_fmaf(xe, bv[kk].w, pa[r][3]);
                    pb[r][0] = __builtin_fmaf(xo, bw[kk].x, pb[r][0]);
                    pb[r][1] = __builtin_fmaf(xo, bw[kk].y, pb[r][1]);
                    pb[r][2] = __builtin_fmaf(xo, bw[kk].z, pb[r][2]);
                    pb[r][3] = __builtin_fmaf(xo, bw[kk].w, pb[r][3]);
                }
        }
#pragma unroll
        for (int r = 0; r < 4; ++r) {
            float* orow = out + (size_t)(o * 512 + ht * 64 + ty * 4 + r) * 512;
            *(float4*)&orow[cb * 64 + tx * 4] =
                make_float4(pa[r][0] + pb[r][0], pa[r][1] + pb[r][1],
                            pa[r][2] + pb[r][2], pa[r][3] + pb[r][3]);
            *(float4*)&orow[256 + cb * 64 + tx * 4] =
                make_float4(pa[r][0] - pb[r][0], pa[r][1] - pb[r][1],
                            pa[r][2] - pb[r][2], pa[r][3] - pb[r][3]);
        }
    }
}

extern "C" void kernel_launch(void* const* d_in, const int* in_sizes, int n_in,
                              void* d_out, int out_size, void* d_ws, size_t ws_size,
                              hipStream_t stream) {
    const float* x  = (const float*)d_in[0];
    const float* Wr = (const float*)d_in[1];
    const float* Wi = (const float*)d_in[2];
    float* out = (float*)d_out;
    float* ws  = (float*)d_ws;

    float* F   = ws + OFF_F;
    float* FA2 = ws + OFF_FA2;
    float* GE2 = ws + OFF_GE2;
    float* GT  = ws + OFF_GT;
    float* XFp = ws + OFF_XFP;
    float* Gp  = ws + OFF_GP;

    build_table<<<128, 256, 0, stream>>>(F, FA2, GE2, GT);
    fusedAB<<<512, 256, 0, stream>>>(x, FA2, GT, XFp);
    stageC<<<512, 256, 0, stream>>>(XFp, Wr, Wi, Gp);
    fusedDE<<<512, 256, 0, stream>>>(F, Gp, GE2, out);
}